// Round 1
// baseline (1598.688 us; speedup 1.0000x reference)
//
#include <hip/hip_runtime.h>

#define NN 50000
#define NE 800000
#define DD 256
#define CC 8
#define HH 64
#define CHW 512   // C*H
#define LN_EPS 1e-5f

// ---------------- GEMM: h0[N,512] = x[N,256] @ proj[256,512] ----------------
// 16-row x 512-col tile per block, 128 threads, 4 cols/thread.
// 50000 % 16 == 0 -> no row guards needed.
__global__ __launch_bounds__(128) void gemm_proj_kernel(
    const float* __restrict__ x, const float* __restrict__ proj,
    float* __restrict__ h0) {
  __shared__ float xs[16 * 256];  // 16 KB
  int tid = threadIdx.x;
  int row0 = blockIdx.x * 16;
  for (int i = tid * 4; i < 16 * 256; i += 128 * 4) {
    *(float4*)(xs + i) = *(const float4*)(x + (size_t)row0 * 256 + i);
  }
  __syncthreads();
  int col = tid * 4;  // 0..508
  float4 acc[16];
#pragma unroll
  for (int r = 0; r < 16; ++r) acc[r] = make_float4(0.f, 0.f, 0.f, 0.f);
  for (int k = 0; k < 256; ++k) {
    float4 p = *(const float4*)(proj + (size_t)k * 512 + col);
#pragma unroll
    for (int r = 0; r < 16; ++r) {
      float xv = xs[r * 256 + k];  // wave-uniform LDS broadcast
      acc[r].x += xv * p.x;
      acc[r].y += xv * p.y;
      acc[r].z += xv * p.z;
      acc[r].w += xv * p.w;
    }
  }
  for (int r = 0; r < 16; ++r) {
    *(float4*)(h0 + (size_t)(row0 + r) * 512 + col) = acc[r];
  }
}

// ---------------- CSR build: histogram -> scan -> fill ----------------
__global__ void hist_kernel(const int* __restrict__ dst, int* __restrict__ cnt) {
  int e = blockIdx.x * 256 + threadIdx.x;
  if (e < NE) atomicAdd(&cnt[dst[e]], 1);
}

// Single-block exclusive scan over NN counts; writes rowptr[0..NN] and also
// writes the exclusive value back into cntcur (it becomes the fill cursor).
__global__ __launch_bounds__(1024) void scan_kernel(int* __restrict__ cntcur,
                                                    int* __restrict__ rowptr) {
  __shared__ int wsum[16];
  __shared__ int carry;
  int tid = threadIdx.x, lane = tid & 63, wv = tid >> 6;
  if (tid == 0) carry = 0;
  __syncthreads();
  for (int base = 0; base < NN; base += 1024) {
    int t = base + tid;
    int orig = (t < NN) ? cntcur[t] : 0;
    int v = orig;
#pragma unroll
    for (int off = 1; off < 64; off <<= 1) {
      int u = __shfl_up(v, off);
      if (lane >= off) v += u;
    }
    if (lane == 63) wsum[wv] = v;
    __syncthreads();
    if (tid < 16) {
      int s = wsum[tid];
#pragma unroll
      for (int off = 1; off < 16; off <<= 1) {
        int u = __shfl_up(s, off);
        if (tid >= off) s += u;
      }
      wsum[tid] = s;
    }
    __syncthreads();
    int run = carry;
    int excl = run + (wv ? wsum[wv - 1] : 0) + (v - orig);
    if (t < NN) {
      rowptr[t] = excl;
      cntcur[t] = excl;
    }
    int blocktotal = wsum[15];
    __syncthreads();
    if (tid == 0) carry = run + blocktotal;
    __syncthreads();
  }
  if (tid == 0) rowptr[NN] = carry;
}

__global__ void fill_kernel(const int* __restrict__ dst, int* __restrict__ cursor,
                            int* __restrict__ eid) {
  int e = blockIdx.x * 256 + threadIdx.x;
  if (e < NE) {
    int d = dst[e];
    int pos = atomicAdd(&cursor[d], 1);
    eid[pos] = e;
  }
}

// ---------------- conv: hnext[n,c,:] = sum_{e in in(n)} omega[e,c]*h[src_e,c,:]
// One block (128 threads) per dst node; thread t handles 4 consecutive floats
// of the 512-float row (c = t>>4). Per edge: one float4 gather per thread.
__global__ __launch_bounds__(128) void conv_kernel(
    const float* __restrict__ h, const float* __restrict__ omega,
    const int* __restrict__ src, const int* __restrict__ rowptr,
    const int* __restrict__ eid, float* __restrict__ hnext) {
  int n = blockIdx.x;
  int t = threadIdx.x;       // 0..127
  int c = t >> 4;            // 0..7
  int start = rowptr[n], end = rowptr[n + 1];
  const float4* h4 = (const float4*)h;
  float4 acc = make_float4(0.f, 0.f, 0.f, 0.f);
  for (int idx = start; idx < end; ++idx) {
    int e = eid[idx];                       // wave-uniform
    int s = src[e];                         // wave-uniform
    float w = omega[(size_t)e * 8 + c];
    float4 hv = h4[(size_t)s * 128 + t];
    acc.x += w * hv.x;
    acc.y += w * hv.y;
    acc.z += w * hv.z;
    acc.w += w * hv.w;
  }
  ((float4*)hnext)[(size_t)n * 128 + t] = acc;
}

// ---------------- bmm + LayerNorm (+ReLU):
// out[n,c,i] = LN_i( sum_k hnext[n,c,k] * W[c,k,i] )
// grid (node_tiles, C); 256 threads = 4 waves; each wave does 8 rows.
template <bool RELU>
__global__ __launch_bounds__(256) void bmm_ln_kernel(
    const float* __restrict__ hnext, const float* __restrict__ W,
    const float* __restrict__ gamma, const float* __restrict__ beta,
    float* __restrict__ out) {
  __shared__ float Ws[64 * 64];  // 16 KB
  int c = blockIdx.y;
  int tid = threadIdx.x, lane = tid & 63, wv = tid >> 6;
  const float* Wc = W + (size_t)c * 4096;
  for (int i = tid * 4; i < 4096; i += 1024) {
    *(float4*)(Ws + i) = *(const float4*)(Wc + i);
  }
  __syncthreads();
  float g = gamma[lane], b = beta[lane];
  int n0 = blockIdx.x * 32 + wv * 8;
  for (int r = 0; r < 8; ++r) {
    int n = n0 + r;
    if (n >= NN) break;
    float a = hnext[(size_t)n * 512 + c * 64 + lane];  // lane holds k=lane
    float o = 0.f;
#pragma unroll
    for (int k = 0; k < 64; ++k) {
      o += __shfl(a, k) * Ws[k * 64 + lane];
    }
    // LayerNorm across the 64 lanes (the H axis)
    float mu = o;
#pragma unroll
    for (int off = 32; off; off >>= 1) mu += __shfl_xor(mu, off);
    mu *= (1.f / 64.f);
    float d = o - mu;
    float var = d * d;
#pragma unroll
    for (int off = 32; off; off >>= 1) var += __shfl_xor(var, off);
    var *= (1.f / 64.f);
    float y = d * rsqrtf(var + LN_EPS) * g + b;
    if (RELU) y = fmaxf(y, 0.f);
    out[(size_t)n * 512 + c * 64 + lane] = y;
  }
}

extern "C" void kernel_launch(void* const* d_in, const int* in_sizes, int n_in,
                              void* d_out, int out_size, void* d_ws, size_t ws_size,
                              hipStream_t stream) {
  const float* x     = (const float*)d_in[0];
  const int*   edge  = (const int*)d_in[1];   // [2,E]: src then dst
  const float* omega = (const float*)d_in[2]; // [E,8]
  const float* proj  = (const float*)d_in[3]; // [256,512]
  const float* W1    = (const float*)d_in[4]; // [8,64,64]
  const float* W2    = (const float*)d_in[5];
  const float* gamma = (const float*)d_in[6];
  const float* beta  = (const float*)d_in[7];
  const int* src = edge;
  const int* dst = edge + NE;
  float* out = (float*)d_out;

  // workspace layout: bufA [N*512 f32] | rowptr [N+1] | cntcur [N] | eid [E]
  float* bufA  = (float*)d_ws;
  int* rowptr  = (int*)((char*)d_ws + (size_t)NN * CHW * 4);
  int* cntcur  = rowptr + (NN + 16);
  int* eid     = cntcur + (NN + 16);

  // ---- CSR build (every call; deterministic work) ----
  hipMemsetAsync(cntcur, 0, NN * sizeof(int), stream);
  hist_kernel<<<(NE + 255) / 256, 256, 0, stream>>>(dst, cntcur);
  scan_kernel<<<1, 1024, 0, stream>>>(cntcur, rowptr);
  fill_kernel<<<(NE + 255) / 256, 256, 0, stream>>>(dst, cntcur, eid);

  // ---- layer 0 ----
  gemm_proj_kernel<<<NN / 16, 128, 0, stream>>>(x, proj, out);  // h0 -> d_out
  conv_kernel<<<NN, 128, 0, stream>>>(out, omega, src, rowptr, eid, bufA);
  bmm_ln_kernel<true><<<dim3((NN + 31) / 32, CC), 256, 0, stream>>>(
      bufA, W1, gamma, beta, out);  // h1 -> d_out

  // ---- layer 1 ----
  conv_kernel<<<NN, 128, 0, stream>>>(out, omega, src, rowptr, eid, bufA);
  bmm_ln_kernel<false><<<dim3((NN + 31) / 32, CC), 256, 0, stream>>>(
      bufA, W2, gamma, beta, out);  // final -> d_out
}

// Round 2
// 1013.461 us; speedup vs baseline: 1.5775x; 1.5775x over previous
//
#include <hip/hip_runtime.h>

#define NN 50000
#define NE 800000
#define DD 256
#define CC 8
#define HH 64
#define CHW 512   // C*H
#define LN_EPS 1e-5f

// ---------------- GEMM: h0[N,512] = x[N,256] @ proj[256,512] ----------------
__global__ __launch_bounds__(128) void gemm_proj_kernel(
    const float* __restrict__ x, const float* __restrict__ proj,
    float* __restrict__ h0) {
  __shared__ float xs[16 * 256];  // 16 KB
  int tid = threadIdx.x;
  int row0 = blockIdx.x * 16;
  for (int i = tid * 4; i < 16 * 256; i += 128 * 4) {
    *(float4*)(xs + i) = *(const float4*)(x + (size_t)row0 * 256 + i);
  }
  __syncthreads();
  int col = tid * 4;  // 0..508
  float4 acc[16];
#pragma unroll
  for (int r = 0; r < 16; ++r) acc[r] = make_float4(0.f, 0.f, 0.f, 0.f);
  for (int k = 0; k < 256; ++k) {
    float4 p = *(const float4*)(proj + (size_t)k * 512 + col);
#pragma unroll
    for (int r = 0; r < 16; ++r) {
      float xv = xs[r * 256 + k];  // wave-uniform LDS broadcast
      acc[r].x += xv * p.x;
      acc[r].y += xv * p.y;
      acc[r].z += xv * p.z;
      acc[r].w += xv * p.w;
    }
  }
  for (int r = 0; r < 16; ++r) {
    *(float4*)(h0 + (size_t)(row0 + r) * 512 + col) = acc[r];
  }
}

// ---------------- CSR build: histogram -> scan -> fill ----------------
__global__ void hist_kernel(const int* __restrict__ dst, int* __restrict__ cnt) {
  int e = blockIdx.x * 256 + threadIdx.x;
  if (e < NE) atomicAdd(&cnt[dst[e]], 1);
}

__global__ __launch_bounds__(1024) void scan_kernel(int* __restrict__ cntcur,
                                                    int* __restrict__ rowptr) {
  __shared__ int wsum[16];
  __shared__ int carry;
  int tid = threadIdx.x, lane = tid & 63, wv = tid >> 6;
  if (tid == 0) carry = 0;
  __syncthreads();
  for (int base = 0; base < NN; base += 1024) {
    int t = base + tid;
    int orig = (t < NN) ? cntcur[t] : 0;
    int v = orig;
#pragma unroll
    for (int off = 1; off < 64; off <<= 1) {
      int u = __shfl_up(v, off);
      if (lane >= off) v += u;
    }
    if (lane == 63) wsum[wv] = v;
    __syncthreads();
    if (tid < 16) {
      int s = wsum[tid];
#pragma unroll
      for (int off = 1; off < 16; off <<= 1) {
        int u = __shfl_up(s, off);
        if (tid >= off) s += u;
      }
      wsum[tid] = s;
    }
    __syncthreads();
    int run = carry;
    int excl = run + (wv ? wsum[wv - 1] : 0) + (v - orig);
    if (t < NN) {
      rowptr[t] = excl;
      cntcur[t] = excl;
    }
    int blocktotal = wsum[15];
    __syncthreads();
    if (tid == 0) carry = run + blocktotal;
    __syncthreads();
  }
  if (tid == 0) rowptr[NN] = carry;
}

__global__ void fill_kernel(const int* __restrict__ dst, int* __restrict__ cursor,
                            int* __restrict__ eid) {
  int e = blockIdx.x * 256 + threadIdx.x;
  if (e < NE) {
    int d = dst[e];
    int pos = atomicAdd(&cursor[d], 1);
    eid[pos] = e;
  }
}

// ---------------- conv: hnext[n,c,:] = sum_{e in in(n)} omega[e,c]*h[src_e,c,:]
__global__ __launch_bounds__(128) void conv_kernel(
    const float* __restrict__ h, const float* __restrict__ omega,
    const int* __restrict__ src, const int* __restrict__ rowptr,
    const int* __restrict__ eid, float* __restrict__ hnext) {
  int n = blockIdx.x;
  int t = threadIdx.x;       // 0..127
  int c = t >> 4;            // 0..7
  int start = rowptr[n], end = rowptr[n + 1];
  const float4* h4 = (const float4*)h;
  float4 acc = make_float4(0.f, 0.f, 0.f, 0.f);
  for (int idx = start; idx < end; ++idx) {
    int e = eid[idx];                       // wave-uniform
    int s = src[e];                         // wave-uniform
    float w = omega[(size_t)e * 8 + c];
    float4 hv = h4[(size_t)s * 128 + t];
    acc.x += w * hv.x;
    acc.y += w * hv.y;
    acc.z += w * hv.z;
    acc.w += w * hv.w;
  }
  ((float4*)hnext)[(size_t)n * 128 + t] = acc;
}

// ---------------- bmm + LayerNorm (+ReLU), register-tiled micro-GEMM ----------
// out[n,c,i] = LN_i( sum_k hnext[n,c,k] * W[c,k,i] )
// Block: 256 threads = 4 waves; block handles 256 rows of one channel.
// Thread (wave wv, lane) = 8x8 tile: rows wv*64 + tr*8 .. +7, cols tc*8 .. +7.
// A staged TRANSPOSED in LDS As[k][row] (pad 264 -> conflict-free b128 reads,
// 16B-aligned rows), in two 32-k phases to keep LDS at ~50 KB (3 blocks/CU).
template <bool RELU>
__global__ __launch_bounds__(256) void bmm_ln_kernel(
    const float* __restrict__ hnext, const float* __restrict__ W,
    const float* __restrict__ gamma, const float* __restrict__ beta,
    float* __restrict__ out) {
  __shared__ float Ws[64 * 64];    // 16 KB
  __shared__ float As[32 * 264];   // 33.8 KB, [k_local][row], pad 264
  const int c = blockIdx.y;
  const int tid = threadIdx.x;
  const int lane = tid & 63, wv = tid >> 6;
  const int tr = lane >> 3, tc = lane & 7;
  const int rloc = wv * 64 + tr * 8;  // local row base (0..248)
  const int col = tc * 8;
  const int n0 = blockIdx.x * 256;

  // stage W[c] (read before first post-stage barrier below)
  const float* Wc = W + (size_t)c * 4096;
  for (int i = tid * 4; i < 4096; i += 1024)
    *(float4*)(Ws + i) = *(const float4*)(Wc + i);

  float acc[8][8];
#pragma unroll
  for (int r = 0; r < 8; ++r)
#pragma unroll
    for (int j = 0; j < 8; ++j) acc[r][j] = 0.f;

  for (int phase = 0; phase < 2; ++phase) {
    const int ko = phase * 32;
    __syncthreads();  // protect As (and, phase 0, order Ws staging)
    // stage As[k_local][row]: 256 rows x 32 k, transposed, coalesced global read
    for (int j = tid; j < 2048; j += 256) {
      int row = j >> 3;   // 0..255
      int kq = j & 7;     // which float4 of the 32-k slab
      int n = n0 + row;
      if (n > NN - 1) n = NN - 1;
      float4 v = *(const float4*)(hnext + (size_t)n * 512 + c * 64 + ko + kq * 4);
      As[(kq * 4 + 0) * 264 + row] = v.x;
      As[(kq * 4 + 1) * 264 + row] = v.y;
      As[(kq * 4 + 2) * 264 + row] = v.z;
      As[(kq * 4 + 3) * 264 + row] = v.w;
    }
    __syncthreads();
#pragma unroll
    for (int k = 0; k < 32; ++k) {
      const float* ap = &As[k * 264 + rloc];
      float4 a0 = *(const float4*)ap;
      float4 a1 = *(const float4*)(ap + 4);
      const float* wp = &Ws[(ko + k) * 64 + col];
      float4 w0 = *(const float4*)wp;
      float4 w1 = *(const float4*)(wp + 4);
      float av[8] = {a0.x, a0.y, a0.z, a0.w, a1.x, a1.y, a1.z, a1.w};
      float wl[8] = {w0.x, w0.y, w0.z, w0.w, w1.x, w1.y, w1.z, w1.w};
#pragma unroll
      for (int r = 0; r < 8; ++r)
#pragma unroll
        for (int j = 0; j < 8; ++j) acc[r][j] += av[r] * wl[j];
    }
  }

  // LayerNorm over the 64 cols (8 local + butterfly over the 8 tc-lanes)
  float g[8], b[8];
  {
    float4 g0 = *(const float4*)(gamma + col);
    float4 g1 = *(const float4*)(gamma + col + 4);
    float4 b0 = *(const float4*)(beta + col);
    float4 b1 = *(const float4*)(beta + col + 4);
    g[0] = g0.x; g[1] = g0.y; g[2] = g0.z; g[3] = g0.w;
    g[4] = g1.x; g[5] = g1.y; g[6] = g1.z; g[7] = g1.w;
    b[0] = b0.x; b[1] = b0.y; b[2] = b0.z; b[3] = b0.w;
    b[4] = b1.x; b[5] = b1.y; b[6] = b1.z; b[7] = b1.w;
  }
#pragma unroll
  for (int r = 0; r < 8; ++r) {
    int n = n0 + rloc + r;
    float s = 0.f;
#pragma unroll
    for (int j = 0; j < 8; ++j) s += acc[r][j];
    s += __shfl_xor(s, 1);
    s += __shfl_xor(s, 2);
    s += __shfl_xor(s, 4);
    float mu = s * (1.f / 64.f);
    float d[8];
    float v = 0.f;
#pragma unroll
    for (int j = 0; j < 8; ++j) {
      d[j] = acc[r][j] - mu;
      v += d[j] * d[j];
    }
    v += __shfl_xor(v, 1);
    v += __shfl_xor(v, 2);
    v += __shfl_xor(v, 4);
    float inv = rsqrtf(v * (1.f / 64.f) + LN_EPS);
    if (n < NN) {
      float o0[4], o1[4];
#pragma unroll
      for (int j = 0; j < 4; ++j) {
        float y = d[j] * inv * g[j] + b[j];
        if (RELU) y = fmaxf(y, 0.f);
        o0[j] = y;
      }
#pragma unroll
      for (int j = 0; j < 4; ++j) {
        float y = d[j + 4] * inv * g[j + 4] + b[j + 4];
        if (RELU) y = fmaxf(y, 0.f);
        o1[j] = y;
      }
      float4* op = (float4*)(out + (size_t)n * 512 + c * 64 + col);
      op[0] = make_float4(o0[0], o0[1], o0[2], o0[3]);
      op[1] = make_float4(o1[0], o1[1], o1[2], o1[3]);
    }
  }
}

extern "C" void kernel_launch(void* const* d_in, const int* in_sizes, int n_in,
                              void* d_out, int out_size, void* d_ws, size_t ws_size,
                              hipStream_t stream) {
  const float* x     = (const float*)d_in[0];
  const int*   edge  = (const int*)d_in[1];   // [2,E]: src then dst
  const float* omega = (const float*)d_in[2]; // [E,8]
  const float* proj  = (const float*)d_in[3]; // [256,512]
  const float* W1    = (const float*)d_in[4]; // [8,64,64]
  const float* W2    = (const float*)d_in[5];
  const float* gamma = (const float*)d_in[6];
  const float* beta  = (const float*)d_in[7];
  const int* src = edge;
  const int* dst = edge + NE;
  float* out = (float*)d_out;

  // workspace layout: bufA [N*512 f32] | rowptr [N+1] | cntcur [N] | eid [E]
  float* bufA  = (float*)d_ws;
  int* rowptr  = (int*)((char*)d_ws + (size_t)NN * CHW * 4);
  int* cntcur  = rowptr + (NN + 16);
  int* eid     = cntcur + (NN + 16);

  // ---- CSR build (every call; deterministic work) ----
  hipMemsetAsync(cntcur, 0, NN * sizeof(int), stream);
  hist_kernel<<<(NE + 255) / 256, 256, 0, stream>>>(dst, cntcur);
  scan_kernel<<<1, 1024, 0, stream>>>(cntcur, rowptr);
  fill_kernel<<<(NE + 255) / 256, 256, 0, stream>>>(dst, cntcur, eid);

  // ---- layer 0 ----
  gemm_proj_kernel<<<NN / 16, 128, 0, stream>>>(x, proj, out);  // h0 -> d_out
  conv_kernel<<<NN, 128, 0, stream>>>(out, omega, src, rowptr, eid, bufA);
  bmm_ln_kernel<true><<<dim3((NN + 255) / 256, CC), 256, 0, stream>>>(
      bufA, W1, gamma, beta, out);  // h1 -> d_out

  // ---- layer 1 ----
  conv_kernel<<<NN, 128, 0, stream>>>(out, omega, src, rowptr, eid, bufA);
  bmm_ln_kernel<false><<<dim3((NN + 255) / 256, CC), 256, 0, stream>>>(
      bufA, W2, gamma, beta, out);  // final -> d_out
}

// Round 3
// 778.283 us; speedup vs baseline: 2.0541x; 1.3022x over previous
//
#include <hip/hip_runtime.h>

#define NN 50000
#define NE 800000
#define DD 256
#define CC 8
#define HH 64
#define CHW 512   // C*H
#define LN_EPS 1e-5f

// round-to-nearest-even f32 -> bf16 (values are finite here)
__device__ inline ushort f2bf(float f) {
  uint u = __float_as_uint(f);
  return (ushort)((u + 0x7fffu + ((u >> 16) & 1u)) >> 16);
}

// ---------------- GEMM: h0[N,512](bf16) = x[N,256] @ proj[256,512] ----------
__global__ __launch_bounds__(128) void gemm_proj_kernel(
    const float* __restrict__ x, const float* __restrict__ proj,
    ushort* __restrict__ h0b) {
  __shared__ float xs[16 * 256];  // 16 KB
  int tid = threadIdx.x;
  int row0 = blockIdx.x * 16;
  for (int i = tid * 4; i < 16 * 256; i += 128 * 4) {
    *(float4*)(xs + i) = *(const float4*)(x + (size_t)row0 * 256 + i);
  }
  __syncthreads();
  int col = tid * 4;  // 0..508
  float4 acc[16];
#pragma unroll
  for (int r = 0; r < 16; ++r) acc[r] = make_float4(0.f, 0.f, 0.f, 0.f);
  for (int k = 0; k < 256; ++k) {
    float4 p = *(const float4*)(proj + (size_t)k * 512 + col);
#pragma unroll
    for (int r = 0; r < 16; ++r) {
      float xv = xs[r * 256 + k];
      acc[r].x += xv * p.x;
      acc[r].y += xv * p.y;
      acc[r].z += xv * p.z;
      acc[r].w += xv * p.w;
    }
  }
  for (int r = 0; r < 16; ++r) {
    ushort4 o;
    o.x = f2bf(acc[r].x); o.y = f2bf(acc[r].y);
    o.z = f2bf(acc[r].z); o.w = f2bf(acc[r].w);
    *(ushort4*)(h0b + (size_t)(row0 + r) * 512 + col) = o;
  }
}

// ---------------- CSR build: histogram -> scan -> fill ----------------
__global__ void hist_kernel(const int* __restrict__ dst, int* __restrict__ cnt) {
  int e = blockIdx.x * 256 + threadIdx.x;
  if (e < NE) atomicAdd(&cnt[dst[e]], 1);
}

__global__ __launch_bounds__(1024) void scan_kernel(int* __restrict__ cntcur,
                                                    int* __restrict__ rowptr) {
  __shared__ int wsum[16];
  __shared__ int carry;
  int tid = threadIdx.x, lane = tid & 63, wv = tid >> 6;
  if (tid == 0) carry = 0;
  __syncthreads();
  for (int base = 0; base < NN; base += 1024) {
    int t = base + tid;
    int orig = (t < NN) ? cntcur[t] : 0;
    int v = orig;
#pragma unroll
    for (int off = 1; off < 64; off <<= 1) {
      int u = __shfl_up(v, off);
      if (lane >= off) v += u;
    }
    if (lane == 63) wsum[wv] = v;
    __syncthreads();
    if (tid < 16) {
      int s = wsum[tid];
#pragma unroll
      for (int off = 1; off < 16; off <<= 1) {
        int u = __shfl_up(s, off);
        if (tid >= off) s += u;
      }
      wsum[tid] = s;
    }
    __syncthreads();
    int run = carry;
    int excl = run + (wv ? wsum[wv - 1] : 0) + (v - orig);
    if (t < NN) {
      rowptr[t] = excl;
      cntcur[t] = excl;
    }
    int blocktotal = wsum[15];
    __syncthreads();
    if (tid == 0) carry = run + blocktotal;
    __syncthreads();
  }
  if (tid == 0) rowptr[NN] = carry;
}

// fill stores (src,e) together: kills the dependent eid->src load in conv
__global__ void fill_kernel(const int* __restrict__ dst, const int* __restrict__ src,
                            int* __restrict__ cursor, int2* __restrict__ epair) {
  int e = blockIdx.x * 256 + threadIdx.x;
  if (e < NE) {
    int d = dst[e];
    int pos = atomicAdd(&cursor[d], 1);
    epair[pos] = make_int2(src[e], e);
  }
}

// ---------------- conv: hnext[n,c,:] = sum_{e in in(n)} omega[e,c]*h[src_e,c,:]
// bf16 gather: one wave per dst node, lane reads 16B (8 bf16) of the 1KB row.
__global__ __launch_bounds__(256) void conv_kernel(
    const ushort* __restrict__ hb, const float* __restrict__ omega,
    const int2* __restrict__ epair, const int* __restrict__ rowptr,
    float* __restrict__ hnext) {
  int n = blockIdx.x * 4 + (threadIdx.x >> 6);
  if (n >= NN) return;
  int lane = threadIdx.x & 63;
  int c = lane >> 3;  // 8 lanes per channel
  int start = rowptr[n], end = rowptr[n + 1];
  const uint4* h4 = (const uint4*)hb;
  float acc[8] = {0.f, 0.f, 0.f, 0.f, 0.f, 0.f, 0.f, 0.f};
  for (int idx = start; idx < end; ++idx) {
    int2 se = epair[idx];                       // wave-uniform
    float w = omega[(size_t)se.y * 8 + c];      // 8-lane broadcast
    uint4 hv = h4[(size_t)se.x * 64 + lane];    // coalesced 1KB/wave
    acc[0] += w * __uint_as_float(hv.x << 16);
    acc[1] += w * __uint_as_float(hv.x & 0xffff0000u);
    acc[2] += w * __uint_as_float(hv.y << 16);
    acc[3] += w * __uint_as_float(hv.y & 0xffff0000u);
    acc[4] += w * __uint_as_float(hv.z << 16);
    acc[5] += w * __uint_as_float(hv.z & 0xffff0000u);
    acc[6] += w * __uint_as_float(hv.w << 16);
    acc[7] += w * __uint_as_float(hv.w & 0xffff0000u);
  }
  float* op = hnext + (size_t)n * 512 + lane * 8;
  *(float4*)op = make_float4(acc[0], acc[1], acc[2], acc[3]);
  *(float4*)(op + 4) = make_float4(acc[4], acc[5], acc[6], acc[7]);
}

// ---------------- bmm + LayerNorm (+ReLU), register-tiled micro-GEMM ----------
// out[n,c,i] = LN_i( sum_k hnext[n,c,k] * W[c,k,i] )
// BF16OUT: write bf16 (feeds the next conv gather); else f32 (final output).
template <bool RELU, bool BF16OUT>
__global__ __launch_bounds__(256) void bmm_ln_kernel(
    const float* __restrict__ hnext, const float* __restrict__ W,
    const float* __restrict__ gamma, const float* __restrict__ beta,
    void* __restrict__ outv) {
  __shared__ float Ws[64 * 64];    // 16 KB
  __shared__ float As[32 * 264];   // 33.8 KB, [k_local][row], pad 264
  const int c = blockIdx.y;
  const int tid = threadIdx.x;
  const int lane = tid & 63, wv = tid >> 6;
  const int tr = lane >> 3, tc = lane & 7;
  const int rloc = wv * 64 + tr * 8;
  const int col = tc * 8;
  const int n0 = blockIdx.x * 256;

  const float* Wc = W + (size_t)c * 4096;
  for (int i = tid * 4; i < 4096; i += 1024)
    *(float4*)(Ws + i) = *(const float4*)(Wc + i);

  float acc[8][8];
#pragma unroll
  for (int r = 0; r < 8; ++r)
#pragma unroll
    for (int j = 0; j < 8; ++j) acc[r][j] = 0.f;

  for (int phase = 0; phase < 2; ++phase) {
    const int ko = phase * 32;
    __syncthreads();
    for (int j = tid; j < 2048; j += 256) {
      int row = j >> 3;
      int kq = j & 7;
      int n = n0 + row;
      if (n > NN - 1) n = NN - 1;
      float4 v = *(const float4*)(hnext + (size_t)n * 512 + c * 64 + ko + kq * 4);
      As[(kq * 4 + 0) * 264 + row] = v.x;
      As[(kq * 4 + 1) * 264 + row] = v.y;
      As[(kq * 4 + 2) * 264 + row] = v.z;
      As[(kq * 4 + 3) * 264 + row] = v.w;
    }
    __syncthreads();
#pragma unroll
    for (int k = 0; k < 32; ++k) {
      const float* ap = &As[k * 264 + rloc];
      float4 a0 = *(const float4*)ap;
      float4 a1 = *(const float4*)(ap + 4);
      const float* wp = &Ws[(ko + k) * 64 + col];
      float4 w0 = *(const float4*)wp;
      float4 w1 = *(const float4*)(wp + 4);
      float av[8] = {a0.x, a0.y, a0.z, a0.w, a1.x, a1.y, a1.z, a1.w};
      float wl[8] = {w0.x, w0.y, w0.z, w0.w, w1.x, w1.y, w1.z, w1.w};
#pragma unroll
      for (int r = 0; r < 8; ++r)
#pragma unroll
        for (int j = 0; j < 8; ++j) acc[r][j] += av[r] * wl[j];
    }
  }

  float g[8], b[8];
  {
    float4 g0 = *(const float4*)(gamma + col);
    float4 g1 = *(const float4*)(gamma + col + 4);
    float4 b0 = *(const float4*)(beta + col);
    float4 b1 = *(const float4*)(beta + col + 4);
    g[0] = g0.x; g[1] = g0.y; g[2] = g0.z; g[3] = g0.w;
    g[4] = g1.x; g[5] = g1.y; g[6] = g1.z; g[7] = g1.w;
    b[0] = b0.x; b[1] = b0.y; b[2] = b0.z; b[3] = b0.w;
    b[4] = b1.x; b[5] = b1.y; b[6] = b1.z; b[7] = b1.w;
  }
#pragma unroll
  for (int r = 0; r < 8; ++r) {
    int n = n0 + rloc + r;
    float s = 0.f;
#pragma unroll
    for (int j = 0; j < 8; ++j) s += acc[r][j];
    s += __shfl_xor(s, 1);
    s += __shfl_xor(s, 2);
    s += __shfl_xor(s, 4);
    float mu = s * (1.f / 64.f);
    float d[8];
    float v = 0.f;
#pragma unroll
    for (int j = 0; j < 8; ++j) {
      d[j] = acc[r][j] - mu;
      v += d[j] * d[j];
    }
    v += __shfl_xor(v, 1);
    v += __shfl_xor(v, 2);
    v += __shfl_xor(v, 4);
    float inv = rsqrtf(v * (1.f / 64.f) + LN_EPS);
    if (n < NN) {
      float y[8];
#pragma unroll
      for (int j = 0; j < 8; ++j) {
        float t = d[j] * inv * g[j] + b[j];
        y[j] = RELU ? fmaxf(t, 0.f) : t;
      }
      if (BF16OUT) {
        ushort o[8];
#pragma unroll
        for (int j = 0; j < 8; ++j) o[j] = f2bf(y[j]);
        *(uint4*)((ushort*)outv + (size_t)n * 512 + c * 64 + col) = *(uint4*)o;
      } else {
        float4* op = (float4*)((float*)outv + (size_t)n * 512 + c * 64 + col);
        op[0] = make_float4(y[0], y[1], y[2], y[3]);
        op[1] = make_float4(y[4], y[5], y[6], y[7]);
      }
    }
  }
}

extern "C" void kernel_launch(void* const* d_in, const int* in_sizes, int n_in,
                              void* d_out, int out_size, void* d_ws, size_t ws_size,
                              hipStream_t stream) {
  const float* x     = (const float*)d_in[0];
  const int*   edge  = (const int*)d_in[1];   // [2,E]: src then dst
  const float* omega = (const float*)d_in[2]; // [E,8]
  const float* proj  = (const float*)d_in[3]; // [256,512]
  const float* W1    = (const float*)d_in[4]; // [8,64,64]
  const float* W2    = (const float*)d_in[5];
  const float* gamma = (const float*)d_in[6];
  const float* beta  = (const float*)d_in[7];
  const int* src = edge;
  const int* dst = edge + NE;

  // ws layout: hbf [N*512 bf16] | rowptr [N+16] | cntcur [N+16] | epair [E int2]
  ushort* hbf = (ushort*)d_ws;
  int* rowptr = (int*)((char*)d_ws + (size_t)NN * CHW * 2);
  int* cntcur = rowptr + (NN + 16);
  int2* epair = (int2*)(cntcur + (NN + 16));
  float* hnext = (float*)d_out;  // f32 conv output lives in d_out

  // ---- CSR build ----
  hipMemsetAsync(cntcur, 0, NN * sizeof(int), stream);
  hist_kernel<<<(NE + 255) / 256, 256, 0, stream>>>(dst, cntcur);
  scan_kernel<<<1, 1024, 0, stream>>>(cntcur, rowptr);
  fill_kernel<<<(NE + 255) / 256, 256, 0, stream>>>(dst, src, cntcur, epair);

  // ---- layer 0 ----
  gemm_proj_kernel<<<NN / 16, 128, 0, stream>>>(x, proj, hbf);  // h0 bf16
  conv_kernel<<<(NN + 3) / 4, 256, 0, stream>>>(hbf, omega, epair, rowptr, hnext);
  bmm_ln_kernel<true, true><<<dim3((NN + 255) / 256, CC), 256, 0, stream>>>(
      hnext, W1, gamma, beta, hbf);  // h1 bf16 (reuses hbf)

  // ---- layer 1 ----
  conv_kernel<<<(NN + 3) / 4, 256, 0, stream>>>(hbf, omega, epair, rowptr, hnext);
  bmm_ln_kernel<false, false><<<dim3((NN + 255) / 256, CC), 256, 0, stream>>>(
      hnext, W2, gamma, beta, d_out);  // final f32, in-place safe per-block
}

// Round 4
// 667.183 us; speedup vs baseline: 2.3962x; 1.1665x over previous
//
#include <hip/hip_runtime.h>

#define NN 50000
#define NE 800000
#define DD 256
#define CC 8
#define HH 64
#define CHW 512   // C*H
#define LN_EPS 1e-5f

typedef __attribute__((ext_vector_type(8))) __bf16 bf16x8;
typedef __attribute__((ext_vector_type(4))) float f32x4;

// round-to-nearest-even f32 -> bf16 (values are finite here)
__device__ inline ushort f2bf(float f) {
  uint u = __float_as_uint(f);
  return (ushort)((u + 0x7fffu + ((u >> 16) & 1u)) >> 16);
}

// ---------------- proj [256][512] f32 -> projT [512][256] bf16 ---------------
__global__ __launch_bounds__(256) void transpose_proj_kernel(
    const float* __restrict__ proj, ushort* __restrict__ projT) {
  __shared__ float t[64][65];
  int k0 = blockIdx.x * 64, n0 = blockIdx.y * 64;
  for (int i = threadIdx.x; i < 1024; i += 256) {
    int k = i >> 4, nq = i & 15;
    float4 v = *(const float4*)(proj + (size_t)(k0 + k) * 512 + n0 + nq * 4);
    t[k][nq * 4 + 0] = v.x;
    t[k][nq * 4 + 1] = v.y;
    t[k][nq * 4 + 2] = v.z;
    t[k][nq * 4 + 3] = v.w;
  }
  __syncthreads();
  for (int i = threadIdx.x; i < 1024; i += 256) {
    int n = i >> 4, kq = i & 15;
    ushort4 o;
    o.x = f2bf(t[kq * 4 + 0][n]);
    o.y = f2bf(t[kq * 4 + 1][n]);
    o.z = f2bf(t[kq * 4 + 2][n]);
    o.w = f2bf(t[kq * 4 + 3][n]);
    *(ushort4*)(projT + (size_t)(n0 + n) * 256 + k0 + kq * 4) = o;
  }
}

// ---------------- MFMA GEMM: h0[N,512](bf16) = x[N,256] @ proj[256,512] ------
// 128x128 tile, 4 waves (2x2), BK=32, 8 K-steps. A=[row][k] pad40, B=[n][k] pad40.
__global__ __launch_bounds__(256) void gemm_proj_kernel(
    const float* __restrict__ x, const ushort* __restrict__ projT,
    ushort* __restrict__ h0b) {
  __shared__ ushort As[128 * 40];  // 10 KB
  __shared__ ushort Bs[128 * 40];  // 10 KB
  const int tid = threadIdx.x;
  const int lane = tid & 63, wv = tid >> 6;
  const int wm = wv >> 1, wn = wv & 1;
  const int lr = lane & 15, kg = lane >> 4;
  const int row0 = blockIdx.x * 128;
  const int col0 = blockIdx.y * 128;

  f32x4 acc[4][4];
#pragma unroll
  for (int i = 0; i < 4; ++i)
#pragma unroll
    for (int j = 0; j < 4; ++j) acc[i][j] = (f32x4){0.f, 0.f, 0.f, 0.f};

  for (int kk = 0; kk < 8; ++kk) {
    __syncthreads();  // protect LDS from previous iteration's reads
    // stage A: 128 rows x 32 k f32 -> bf16 (1024 float4s / 256 thr = 4 each)
#pragma unroll
    for (int i = 0; i < 4; ++i) {
      int idx = tid + i * 256;
      int row = idx >> 3, quad = idx & 7;
      int rg = row0 + row;
      rg = rg < NN ? rg : NN - 1;
      float4 v = *(const float4*)(x + (size_t)rg * 256 + kk * 32 + quad * 4);
      ushort4 o = {f2bf(v.x), f2bf(v.y), f2bf(v.z), f2bf(v.w)};
      *(ushort4*)(As + row * 40 + quad * 4) = o;
    }
    // stage B: 128 n-rows x 32 k bf16 (512 uint4s / 256 thr = 2 each)
#pragma unroll
    for (int i = 0; i < 2; ++i) {
      int idx = tid + i * 256;
      int n = idx >> 2, quad = idx & 3;
      uint4 v = *(const uint4*)(projT + (size_t)(col0 + n) * 256 + kk * 32 + quad * 8);
      *(uint4*)(Bs + n * 40 + quad * 8) = v;
    }
    __syncthreads();
    bf16x8 a[4], b[4];
#pragma unroll
    for (int i = 0; i < 4; ++i)
      a[i] = *(const bf16x8*)(As + (wm * 64 + i * 16 + lr) * 40 + kg * 8);
#pragma unroll
    for (int j = 0; j < 4; ++j)
      b[j] = *(const bf16x8*)(Bs + (wn * 64 + j * 16 + lr) * 40 + kg * 8);
#pragma unroll
    for (int i = 0; i < 4; ++i)
#pragma unroll
      for (int j = 0; j < 4; ++j)
        acc[i][j] = __builtin_amdgcn_mfma_f32_16x16x32_bf16(a[i], b[j], acc[i][j], 0, 0, 0);
  }

  // epilogue: C/D layout col=lane&15, row=(lane>>4)*4+q  (m89-verified)
  const int orow = kg * 4;
  const int ocol = lane & 15;
#pragma unroll
  for (int i = 0; i < 4; ++i) {
    int rg0 = row0 + wm * 64 + i * 16 + orow;
#pragma unroll
    for (int q = 0; q < 4; ++q) {
      int rg = rg0 + q;
      if (rg < NN) {
#pragma unroll
        for (int j = 0; j < 4; ++j) {
          h0b[(size_t)rg * 512 + col0 + wn * 64 + j * 16 + ocol] = f2bf(acc[i][j][q]);
        }
      }
    }
  }
}

// ---------------- CSR build: histogram -> scan -> fill ----------------
__global__ void hist_kernel(const int* __restrict__ dst, int* __restrict__ cnt) {
  int e = blockIdx.x * 256 + threadIdx.x;
  if (e < NE) atomicAdd(&cnt[dst[e]], 1);
}

__global__ __launch_bounds__(1024) void scan_kernel(int* __restrict__ cntcur,
                                                    int* __restrict__ rowptr) {
  __shared__ int wsum[16];
  __shared__ int carry;
  int tid = threadIdx.x, lane = tid & 63, wv = tid >> 6;
  if (tid == 0) carry = 0;
  __syncthreads();
  for (int base = 0; base < NN; base += 1024) {
    int t = base + tid;
    int orig = (t < NN) ? cntcur[t] : 0;
    int v = orig;
#pragma unroll
    for (int off = 1; off < 64; off <<= 1) {
      int u = __shfl_up(v, off);
      if (lane >= off) v += u;
    }
    if (lane == 63) wsum[wv] = v;
    __syncthreads();
    if (tid < 16) {
      int s = wsum[tid];
#pragma unroll
      for (int off = 1; off < 16; off <<= 1) {
        int u = __shfl_up(s, off);
        if (tid >= off) s += u;
      }
      wsum[tid] = s;
    }
    __syncthreads();
    int run = carry;
    int excl = run + (wv ? wsum[wv - 1] : 0) + (v - orig);
    if (t < NN) {
      rowptr[t] = excl;
      cntcur[t] = excl;
    }
    int blocktotal = wsum[15];
    __syncthreads();
    if (tid == 0) carry = run + blocktotal;
    __syncthreads();
  }
  if (tid == 0) rowptr[NN] = carry;
}

// fill stores (src,e) together: kills the dependent eid->src load in conv
__global__ void fill_kernel(const int* __restrict__ dst, const int* __restrict__ src,
                            int* __restrict__ cursor, int2* __restrict__ epair) {
  int e = blockIdx.x * 256 + threadIdx.x;
  if (e < NE) {
    int d = dst[e];
    int pos = atomicAdd(&cursor[d], 1);
    epair[pos] = make_int2(src[e], e);
  }
}

// ---------------- conv: hnext[n,c,:] = sum_{e in in(n)} omega[e,c]*h[src_e,c,:]
// bf16 gather: one wave per dst node, lane reads 16B (8 bf16) of the 1KB row.
__global__ __launch_bounds__(256) void conv_kernel(
    const ushort* __restrict__ hb, const float* __restrict__ omega,
    const int2* __restrict__ epair, const int* __restrict__ rowptr,
    float* __restrict__ hnext) {
  int n = blockIdx.x * 4 + (threadIdx.x >> 6);
  if (n >= NN) return;
  int lane = threadIdx.x & 63;
  int c = lane >> 3;  // 8 lanes per channel
  int start = rowptr[n], end = rowptr[n + 1];
  const uint4* h4 = (const uint4*)hb;
  float acc[8] = {0.f, 0.f, 0.f, 0.f, 0.f, 0.f, 0.f, 0.f};
  for (int idx = start; idx < end; ++idx) {
    int2 se = epair[idx];                       // wave-uniform
    float w = omega[(size_t)se.y * 8 + c];      // 8-lane broadcast
    uint4 hv = h4[(size_t)se.x * 64 + lane];    // coalesced 1KB/wave
    acc[0] += w * __uint_as_float(hv.x << 16);
    acc[1] += w * __uint_as_float(hv.x & 0xffff0000u);
    acc[2] += w * __uint_as_float(hv.y << 16);
    acc[3] += w * __uint_as_float(hv.y & 0xffff0000u);
    acc[4] += w * __uint_as_float(hv.z << 16);
    acc[5] += w * __uint_as_float(hv.z & 0xffff0000u);
    acc[6] += w * __uint_as_float(hv.w << 16);
    acc[7] += w * __uint_as_float(hv.w & 0xffff0000u);
  }
  float* op = hnext + (size_t)n * 512 + lane * 8;
  *(float4*)op = make_float4(acc[0], acc[1], acc[2], acc[3]);
  *(float4*)(op + 4) = make_float4(acc[4], acc[5], acc[6], acc[7]);
}

// ---------------- bmm + LayerNorm (+ReLU), register-tiled micro-GEMM ----------
// out[n,c,i] = LN_i( sum_k hnext[n,c,k] * W[c,k,i] )
// BF16OUT: write bf16 (feeds the next conv gather); else f32 (final output).
template <bool RELU, bool BF16OUT>
__global__ __launch_bounds__(256) void bmm_ln_kernel(
    const float* __restrict__ hnext, const float* __restrict__ W,
    const float* __restrict__ gamma, const float* __restrict__ beta,
    void* __restrict__ outv) {
  __shared__ float Ws[64 * 64];    // 16 KB
  __shared__ float As[32 * 264];   // 33.8 KB, [k_local][row], pad 264
  const int c = blockIdx.y;
  const int tid = threadIdx.x;
  const int lane = tid & 63, wv = tid >> 6;
  const int tr = lane >> 3, tc = lane & 7;
  const int rloc = wv * 64 + tr * 8;
  const int col = tc * 8;
  const int n0 = blockIdx.x * 256;

  const float* Wc = W + (size_t)c * 4096;
  for (int i = tid * 4; i < 4096; i += 1024)
    *(float4*)(Ws + i) = *(const float4*)(Wc + i);

  float acc[8][8];
#pragma unroll
  for (int r = 0; r < 8; ++r)
#pragma unroll
    for (int j = 0; j < 8; ++j) acc[r][j] = 0.f;

  for (int phase = 0; phase < 2; ++phase) {
    const int ko = phase * 32;
    __syncthreads();
    for (int j = tid; j < 2048; j += 256) {
      int row = j >> 3;
      int kq = j & 7;
      int n = n0 + row;
      if (n > NN - 1) n = NN - 1;
      float4 v = *(const float4*)(hnext + (size_t)n * 512 + c * 64 + ko + kq * 4);
      As[(kq * 4 + 0) * 264 + row] = v.x;
      As[(kq * 4 + 1) * 264 + row] = v.y;
      As[(kq * 4 + 2) * 264 + row] = v.z;
      As[(kq * 4 + 3) * 264 + row] = v.w;
    }
    __syncthreads();
#pragma unroll
    for (int k = 0; k < 32; ++k) {
      const float* ap = &As[k * 264 + rloc];
      float4 a0 = *(const float4*)ap;
      float4 a1 = *(const float4*)(ap + 4);
      const float* wp = &Ws[(ko + k) * 64 + col];
      float4 w0 = *(const float4*)wp;
      float4 w1 = *(const float4*)(wp + 4);
      float av[8] = {a0.x, a0.y, a0.z, a0.w, a1.x, a1.y, a1.z, a1.w};
      float wl[8] = {w0.x, w0.y, w0.z, w0.w, w1.x, w1.y, w1.z, w1.w};
#pragma unroll
      for (int r = 0; r < 8; ++r)
#pragma unroll
        for (int j = 0; j < 8; ++j) acc[r][j] += av[r] * wl[j];
    }
  }

  float g[8], b[8];
  {
    float4 g0 = *(const float4*)(gamma + col);
    float4 g1 = *(const float4*)(gamma + col + 4);
    float4 b0 = *(const float4*)(beta + col);
    float4 b1 = *(const float4*)(beta + col + 4);
    g[0] = g0.x; g[1] = g0.y; g[2] = g0.z; g[3] = g0.w;
    g[4] = g1.x; g[5] = g1.y; g[6] = g1.z; g[7] = g1.w;
    b[0] = b0.x; b[1] = b0.y; b[2] = b0.z; b[3] = b0.w;
    b[4] = b1.x; b[5] = b1.y; b[6] = b1.z; b[7] = b1.w;
  }
#pragma unroll
  for (int r = 0; r < 8; ++r) {
    int n = n0 + rloc + r;
    float s = 0.f;
#pragma unroll
    for (int j = 0; j < 8; ++j) s += acc[r][j];
    s += __shfl_xor(s, 1);
    s += __shfl_xor(s, 2);
    s += __shfl_xor(s, 4);
    float mu = s * (1.f / 64.f);
    float d[8];
    float v = 0.f;
#pragma unroll
    for (int j = 0; j < 8; ++j) {
      d[j] = acc[r][j] - mu;
      v += d[j] * d[j];
    }
    v += __shfl_xor(v, 1);
    v += __shfl_xor(v, 2);
    v += __shfl_xor(v, 4);
    float inv = rsqrtf(v * (1.f / 64.f) + LN_EPS);
    if (n < NN) {
      float y[8];
#pragma unroll
      for (int j = 0; j < 8; ++j) {
        float t = d[j] * inv * g[j] + b[j];
        y[j] = RELU ? fmaxf(t, 0.f) : t;
      }
      if (BF16OUT) {
        ushort o[8];
#pragma unroll
        for (int j = 0; j < 8; ++j) o[j] = f2bf(y[j]);
        *(uint4*)((ushort*)outv + (size_t)n * 512 + c * 64 + col) = *(uint4*)o;
      } else {
        float4* op = (float4*)((float*)outv + (size_t)n * 512 + c * 64 + col);
        op[0] = make_float4(y[0], y[1], y[2], y[3]);
        op[1] = make_float4(y[4], y[5], y[6], y[7]);
      }
    }
  }
}

extern "C" void kernel_launch(void* const* d_in, const int* in_sizes, int n_in,
                              void* d_out, int out_size, void* d_ws, size_t ws_size,
                              hipStream_t stream) {
  const float* x     = (const float*)d_in[0];
  const int*   edge  = (const int*)d_in[1];   // [2,E]: src then dst
  const float* omega = (const float*)d_in[2]; // [E,8]
  const float* proj  = (const float*)d_in[3]; // [256,512]
  const float* W1    = (const float*)d_in[4]; // [8,64,64]
  const float* W2    = (const float*)d_in[5];
  const float* gamma = (const float*)d_in[6];
  const float* beta  = (const float*)d_in[7];
  const int* src = edge;
  const int* dst = edge + NE;

  // ws: hbf [N*512 bf16] | rowptr [N+16] | cntcur [N+16] | epair [E int2] | projT
  ushort* hbf = (ushort*)d_ws;
  int* rowptr = (int*)((char*)d_ws + (size_t)NN * CHW * 2);
  int* cntcur = rowptr + (NN + 16);
  int2* epair = (int2*)(cntcur + (NN + 16));
  ushort* projT = (ushort*)(epair + NE);
  float* hnext = (float*)d_out;  // f32 conv output lives in d_out

  // ---- CSR build ----
  hipMemsetAsync(cntcur, 0, NN * sizeof(int), stream);
  hist_kernel<<<(NE + 255) / 256, 256, 0, stream>>>(dst, cntcur);
  scan_kernel<<<1, 1024, 0, stream>>>(cntcur, rowptr);
  fill_kernel<<<(NE + 255) / 256, 256, 0, stream>>>(dst, src, cntcur, epair);

  // ---- layer 0 ----
  transpose_proj_kernel<<<dim3(4, 8), 256, 0, stream>>>(proj, projT);
  gemm_proj_kernel<<<dim3((NN + 127) / 128, 4), 256, 0, stream>>>(x, projT, hbf);
  conv_kernel<<<(NN + 3) / 4, 256, 0, stream>>>(hbf, omega, epair, rowptr, hnext);
  bmm_ln_kernel<true, true><<<dim3((NN + 255) / 256, CC), 256, 0, stream>>>(
      hnext, W1, gamma, beta, hbf);  // h1 bf16 (reuses hbf)

  // ---- layer 1 ----
  conv_kernel<<<(NN + 3) / 4, 256, 0, stream>>>(hbf, omega, epair, rowptr, hnext);
  bmm_ln_kernel<false, false><<<dim3((NN + 255) / 256, CC), 256, 0, stream>>>(
      hnext, W2, gamma, beta, d_out);  // final f32, in-place safe per-block
}

// Round 5
// 503.090 us; speedup vs baseline: 3.1777x; 1.3262x over previous
//
#include <hip/hip_runtime.h>

#define NN 50000
#define NE 800000
#define DD 256
#define CC 8
#define HH 64
#define CHW 512   // C*H
#define LN_EPS 1e-5f

typedef __attribute__((ext_vector_type(8))) __bf16 bf16x8;
typedef __attribute__((ext_vector_type(4))) float f32x4;

// round-to-nearest-even f32 -> bf16 (values are finite here)
__device__ inline ushort f2bf(float f) {
  uint u = __float_as_uint(f);
  return (ushort)((u + 0x7fffu + ((u >> 16) & 1u)) >> 16);
}

// ---------------- fold: projW1T[n][d] = sum_k proj[d][c*64+k] * W1[c][k][i]
// n = c*64+i; output is the B-operand layout [n][k=d] bf16 for the MFMA gemm.
__global__ __launch_bounds__(256) void fold_w1_kernel(
    const float* __restrict__ proj, const float* __restrict__ W1,
    ushort* __restrict__ projW1T) {
  __shared__ float wl[64];
  const int n = blockIdx.x;           // 0..511
  const int c = n >> 6, i = n & 63;
  const int tid = threadIdx.x;
  if (tid < 64) wl[tid] = W1[c * 4096 + tid * 64 + i];
  __syncthreads();
  const float* pr = proj + (size_t)tid * 512 + c * 64;  // row d = tid
  float acc = 0.f;
#pragma unroll
  for (int k = 0; k < 64; ++k) acc += pr[k] * wl[k];
  projW1T[(size_t)n * 256 + tid] = f2bf(acc);
}

// ---------------- W2T[c][n][k] = W2[c][k][n], bf16 (B-operand layout) --------
__global__ __launch_bounds__(256) void w2t_kernel(const float* __restrict__ W2,
                                                  ushort* __restrict__ W2T) {
  int c = blockIdx.x;
  for (int idx = threadIdx.x; idx < 4096; idx += 256) {
    int nn = idx >> 6, k = idx & 63;
    W2T[(size_t)c * 4096 + idx] = f2bf(W2[(size_t)c * 4096 + k * 64 + nn]);
  }
}

// ---------------- MFMA GEMM: g1[N,512](bf16) = x[N,256] @ projW1 -------------
// 128x128 tile, 4 waves (2x2), BK=32, 8 K-steps. A=[row][k] pad40, B=[n][k] pad40.
__global__ __launch_bounds__(256) void gemm_proj_kernel(
    const float* __restrict__ x, const ushort* __restrict__ BT,
    ushort* __restrict__ gout) {
  __shared__ ushort As[128 * 40];  // 10 KB
  __shared__ ushort Bs[128 * 40];  // 10 KB
  const int tid = threadIdx.x;
  const int lane = tid & 63, wv = tid >> 6;
  const int wm = wv >> 1, wn = wv & 1;
  const int lr = lane & 15, kg = lane >> 4;
  const int row0 = blockIdx.x * 128;
  const int col0 = blockIdx.y * 128;

  f32x4 acc[4][4];
#pragma unroll
  for (int i = 0; i < 4; ++i)
#pragma unroll
    for (int j = 0; j < 4; ++j) acc[i][j] = (f32x4){0.f, 0.f, 0.f, 0.f};

  for (int kk = 0; kk < 8; ++kk) {
    __syncthreads();
#pragma unroll
    for (int i = 0; i < 4; ++i) {
      int idx = tid + i * 256;
      int row = idx >> 3, quad = idx & 7;
      int rg = row0 + row;
      rg = rg < NN ? rg : NN - 1;
      float4 v = *(const float4*)(x + (size_t)rg * 256 + kk * 32 + quad * 4);
      ushort4 o = {f2bf(v.x), f2bf(v.y), f2bf(v.z), f2bf(v.w)};
      *(ushort4*)(As + row * 40 + quad * 4) = o;
    }
#pragma unroll
    for (int i = 0; i < 2; ++i) {
      int idx = tid + i * 256;
      int n = idx >> 2, quad = idx & 3;
      uint4 v = *(const uint4*)(BT + (size_t)(col0 + n) * 256 + kk * 32 + quad * 8);
      *(uint4*)(Bs + n * 40 + quad * 8) = v;
    }
    __syncthreads();
    bf16x8 a[4], b[4];
#pragma unroll
    for (int i = 0; i < 4; ++i)
      a[i] = *(const bf16x8*)(As + (wm * 64 + i * 16 + lr) * 40 + kg * 8);
#pragma unroll
    for (int j = 0; j < 4; ++j)
      b[j] = *(const bf16x8*)(Bs + (wn * 64 + j * 16 + lr) * 40 + kg * 8);
#pragma unroll
    for (int i = 0; i < 4; ++i)
#pragma unroll
      for (int j = 0; j < 4; ++j)
        acc[i][j] = __builtin_amdgcn_mfma_f32_16x16x32_bf16(a[i], b[j], acc[i][j], 0, 0, 0);
  }

  const int orow = kg * 4;
  const int ocol = lane & 15;
#pragma unroll
  for (int i = 0; i < 4; ++i) {
    int rg0 = row0 + wm * 64 + i * 16 + orow;
#pragma unroll
    for (int q = 0; q < 4; ++q) {
      int rg = rg0 + q;
      if (rg < NN) {
#pragma unroll
        for (int j = 0; j < 4; ++j) {
          gout[(size_t)rg * 512 + col0 + wn * 64 + j * 16 + ocol] = f2bf(acc[i][j][q]);
        }
      }
    }
  }
}

// ---------------- bmm: g2[n, c*64..] = h1[n, c*64..] @ W2[c]  (bf16 MFMA) ----
// Block: 128 rows x one channel (64 cols). 4 waves, wave = 32 rows.
__global__ __launch_bounds__(256) void bmm_g_kernel(
    const ushort* __restrict__ h, const ushort* __restrict__ WT,
    ushort* __restrict__ g) {
  __shared__ ushort As[128 * 72];   // 18 KB
  __shared__ ushort Bs[64 * 72];    // 9 KB
  __shared__ float Cs[4][32 * 68];  // 34.8 KB  (f32 bounce for coalesced stores)
  const int tid = threadIdx.x, lane = tid & 63, wv = tid >> 6;
  const int lr = lane & 15, kg = lane >> 4;
  const int n0 = blockIdx.x * 128;
  const int c = blockIdx.y;

#pragma unroll
  for (int i = 0; i < 4; ++i) {
    int idx = tid + i * 256;
    int row = idx >> 3, q = idx & 7;
    int rg = n0 + row;
    rg = rg < NN ? rg : NN - 1;
    *(uint4*)(As + row * 72 + q * 8) =
        *(const uint4*)(h + (size_t)rg * 512 + c * 64 + q * 8);
  }
#pragma unroll
  for (int i = 0; i < 2; ++i) {
    int idx = tid + i * 256;
    int row = idx >> 3, q = idx & 7;
    *(uint4*)(Bs + row * 72 + q * 8) =
        *(const uint4*)(WT + (size_t)c * 4096 + row * 64 + q * 8);
  }
  __syncthreads();

  f32x4 acc[2][4];
#pragma unroll
  for (int m = 0; m < 2; ++m)
#pragma unroll
    for (int j = 0; j < 4; ++j) acc[m][j] = (f32x4){0.f, 0.f, 0.f, 0.f};

#pragma unroll
  for (int ks = 0; ks < 2; ++ks) {
    bf16x8 a[2], b[4];
#pragma unroll
    for (int m = 0; m < 2; ++m)
      a[m] = *(const bf16x8*)(As + (wv * 32 + m * 16 + lr) * 72 + ks * 32 + kg * 8);
#pragma unroll
    for (int j = 0; j < 4; ++j)
      b[j] = *(const bf16x8*)(Bs + (j * 16 + lr) * 72 + ks * 32 + kg * 8);
#pragma unroll
    for (int m = 0; m < 2; ++m)
#pragma unroll
      for (int j = 0; j < 4; ++j)
        acc[m][j] = __builtin_amdgcn_mfma_f32_16x16x32_bf16(a[m], b[j], acc[m][j], 0, 0, 0);
  }

  float* cs = &Cs[wv][0];
#pragma unroll
  for (int m = 0; m < 2; ++m)
#pragma unroll
    for (int j = 0; j < 4; ++j)
#pragma unroll
      for (int q = 0; q < 4; ++q)
        cs[(m * 16 + kg * 4 + q) * 68 + j * 16 + lr] = acc[m][j][q];
  __syncthreads();

  const int row = lane & 31, half = lane >> 5;
  const int rg = n0 + wv * 32 + row;
  if (rg < NN) {
    const float* rp = cs + row * 68 + half * 32;
    ushort ob[32];
#pragma unroll
    for (int t = 0; t < 32; ++t) ob[t] = f2bf(rp[t]);
    ushort* op = g + (size_t)rg * 512 + c * 64 + half * 32;
#pragma unroll
    for (int t = 0; t < 4; ++t)
      *(uint4*)(op + t * 8) = *(uint4*)(ob + t * 8);
  }
}

// ---------------- CSR build: histogram -> scan -> fill ----------------
__global__ void hist_kernel(const int* __restrict__ dst, int* __restrict__ cnt) {
  int e = blockIdx.x * 256 + threadIdx.x;
  if (e < NE) atomicAdd(&cnt[dst[e]], 1);
}

__global__ __launch_bounds__(1024) void scan_kernel(int* __restrict__ cntcur,
                                                    int* __restrict__ rowptr) {
  __shared__ int wsum[16];
  __shared__ int carry;
  int tid = threadIdx.x, lane = tid & 63, wv = tid >> 6;
  if (tid == 0) carry = 0;
  __syncthreads();
  for (int base = 0; base < NN; base += 1024) {
    int t = base + tid;
    int orig = (t < NN) ? cntcur[t] : 0;
    int v = orig;
#pragma unroll
    for (int off = 1; off < 64; off <<= 1) {
      int u = __shfl_up(v, off);
      if (lane >= off) v += u;
    }
    if (lane == 63) wsum[wv] = v;
    __syncthreads();
    if (tid < 16) {
      int s = wsum[tid];
#pragma unroll
      for (int off = 1; off < 16; off <<= 1) {
        int u = __shfl_up(s, off);
        if (tid >= off) s += u;
      }
      wsum[tid] = s;
    }
    __syncthreads();
    int run = carry;
    int excl = run + (wv ? wsum[wv - 1] : 0) + (v - orig);
    if (t < NN) {
      rowptr[t] = excl;
      cntcur[t] = excl;
    }
    int blocktotal = wsum[15];
    __syncthreads();
    if (tid == 0) carry = run + blocktotal;
    __syncthreads();
  }
  if (tid == 0) rowptr[NN] = carry;
}

// fill: CSR payload = src node + omega row packed f16x8 (all streaming in conv)
__global__ void fill_kernel(const int* __restrict__ dst, const int* __restrict__ src,
                            const float* __restrict__ omega, int* __restrict__ cursor,
                            int* __restrict__ esrc, uint4* __restrict__ eom) {
  int e = blockIdx.x * 256 + threadIdx.x;
  if (e < NE) {
    int d = dst[e];
    int pos = atomicAdd(&cursor[d], 1);
    esrc[pos] = src[e];
    const float4* om4 = (const float4*)(omega + (size_t)e * 8);
    float4 o0 = om4[0], o1 = om4[1];
    union { _Float16 f[8]; uint4 v; } pk;
    pk.f[0] = (_Float16)o0.x; pk.f[1] = (_Float16)o0.y;
    pk.f[2] = (_Float16)o0.z; pk.f[3] = (_Float16)o0.w;
    pk.f[4] = (_Float16)o1.x; pk.f[5] = (_Float16)o1.y;
    pk.f[6] = (_Float16)o1.z; pk.f[7] = (_Float16)o1.w;
    eom[pos] = pk.v;
  }
}

// ---------------- conv + LayerNorm (+ReLU) fused:
// out[n,c,:] = LN( sum_{e in in(n)} omega[e,c] * g[src_e, c, :] )
// One wave per node; lane covers 8 bf16 of the row; LN via 8-lane shuffles.
template <bool RELU, bool BF16OUT>
__global__ __launch_bounds__(256) void conv_ln_kernel(
    const ushort* __restrict__ g, const int* __restrict__ esrc,
    const uint4* __restrict__ eom, const int* __restrict__ rowptr,
    const float* __restrict__ gamma, const float* __restrict__ beta,
    void* __restrict__ outv) {
  int n = blockIdx.x * 4 + (threadIdx.x >> 6);
  if (n >= NN) return;
  const int lane = threadIdx.x & 63;
  const int c = lane >> 3;          // channel of this lane
  const int i0 = (lane & 7) * 8;    // H-offset of this lane's 8 elements
  int start = rowptr[n], end = rowptr[n + 1];
  const uint4* g4 = (const uint4*)g;
  float acc[8] = {0.f, 0.f, 0.f, 0.f, 0.f, 0.f, 0.f, 0.f};
  for (int idx = start; idx < end; ++idx) {
    int s = esrc[idx];                          // wave-uniform
    uint4 om = eom[idx];                        // wave-uniform 16B
    uint wd = (c & 2) ? ((c & 4) ? om.w : om.y) : ((c & 4) ? om.z : om.x);
    ushort hu = (c & 1) ? (ushort)(wd >> 16) : (ushort)(wd & 0xffffu);
    union { ushort u; _Float16 f; } cv; cv.u = hu;
    float w = (float)cv.f;
    uint4 hv = g4[(size_t)s * 64 + lane];       // coalesced 1KB/wave gather
    acc[0] += w * __uint_as_float(hv.x << 16);
    acc[1] += w * __uint_as_float(hv.x & 0xffff0000u);
    acc[2] += w * __uint_as_float(hv.y << 16);
    acc[3] += w * __uint_as_float(hv.y & 0xffff0000u);
    acc[4] += w * __uint_as_float(hv.z << 16);
    acc[5] += w * __uint_as_float(hv.z & 0xffff0000u);
    acc[6] += w * __uint_as_float(hv.w << 16);
    acc[7] += w * __uint_as_float(hv.w & 0xffff0000u);
  }
  // LayerNorm over the 64 H-values of channel c (8 lanes x 8 each)
  float s8 = ((acc[0] + acc[1]) + (acc[2] + acc[3])) +
             ((acc[4] + acc[5]) + (acc[6] + acc[7]));
  s8 += __shfl_xor(s8, 1);
  s8 += __shfl_xor(s8, 2);
  s8 += __shfl_xor(s8, 4);
  float mu = s8 * (1.f / 64.f);
  float d[8];
  float v = 0.f;
#pragma unroll
  for (int j = 0; j < 8; ++j) {
    d[j] = acc[j] - mu;
    v += d[j] * d[j];
  }
  v += __shfl_xor(v, 1);
  v += __shfl_xor(v, 2);
  v += __shfl_xor(v, 4);
  float inv = rsqrtf(v * (1.f / 64.f) + LN_EPS);
  float4 g0 = *(const float4*)(gamma + i0);
  float4 g1 = *(const float4*)(gamma + i0 + 4);
  float4 b0 = *(const float4*)(beta + i0);
  float4 b1 = *(const float4*)(beta + i0 + 4);
  float gg[8] = {g0.x, g0.y, g0.z, g0.w, g1.x, g1.y, g1.z, g1.w};
  float bb[8] = {b0.x, b0.y, b0.z, b0.w, b1.x, b1.y, b1.z, b1.w};
  float y[8];
#pragma unroll
  for (int j = 0; j < 8; ++j) {
    float t = d[j] * inv * gg[j] + bb[j];
    y[j] = RELU ? fmaxf(t, 0.f) : t;
  }
  if (BF16OUT) {
    ushort o[8];
#pragma unroll
    for (int j = 0; j < 8; ++j) o[j] = f2bf(y[j]);
    *(uint4*)((ushort*)outv + (size_t)n * 512 + c * 64 + i0) = *(uint4*)o;
  } else {
    float* op = (float*)outv + (size_t)n * 512 + c * 64 + i0;
    *(float4*)op = make_float4(y[0], y[1], y[2], y[3]);
    *(float4*)(op + 4) = make_float4(y[4], y[5], y[6], y[7]);
  }
}

extern "C" void kernel_launch(void* const* d_in, const int* in_sizes, int n_in,
                              void* d_out, int out_size, void* d_ws, size_t ws_size,
                              hipStream_t stream) {
  const float* x     = (const float*)d_in[0];
  const int*   edge  = (const int*)d_in[1];   // [2,E]: src then dst
  const float* omega = (const float*)d_in[2]; // [E,8]
  const float* proj  = (const float*)d_in[3]; // [256,512]
  const float* W1    = (const float*)d_in[4]; // [8,64,64]
  const float* W2    = (const float*)d_in[5];
  const float* gamma = (const float*)d_in[6];
  const float* beta  = (const float*)d_in[7];
  const int* src = edge;
  const int* dst = edge + NE;

  // ws layout (all 16B-aligned): hbf | eom | esrc | rowptr | cntcur | projW1T | W2T
  char* p = (char*)d_ws;
  ushort* hbf    = (ushort*)p;              p += (size_t)NN * CHW * 2;   // 51.2 MB
  uint4*  eom    = (uint4*)p;               p += (size_t)NE * 16;        // 12.8 MB
  int*    esrc   = (int*)p;                 p += (size_t)NE * 4;         // 3.2 MB
  int*    rowptr = (int*)p;                 p += (size_t)(NN + 16) * 4;
  int*    cntcur = (int*)p;                 p += (size_t)(NN + 16) * 4;
  ushort* projW1T= (ushort*)p;              p += (size_t)512 * 256 * 2;
  ushort* W2T    = (ushort*)p;

  ushort* h1 = (ushort*)d_out;  // h1 bf16 lives in d_out's first half (dead
                                // before the final f32 write overwrites it)

  // ---- CSR build ----
  hipMemsetAsync(cntcur, 0, NN * sizeof(int), stream);
  hist_kernel<<<(NE + 255) / 256, 256, 0, stream>>>(dst, cntcur);
  scan_kernel<<<1, 1024, 0, stream>>>(cntcur, rowptr);
  fill_kernel<<<(NE + 255) / 256, 256, 0, stream>>>(dst, src, omega, cntcur, esrc, eom);

  // ---- parameter prep ----
  fold_w1_kernel<<<512, 256, 0, stream>>>(proj, W1, projW1T);  // proj·W1 folded
  w2t_kernel<<<8, 256, 0, stream>>>(W2, W2T);

  // ---- layer 0: g1 = x @ projW1  ->  h1 = ReLU(LN(gather(g1))) ----
  gemm_proj_kernel<<<dim3((NN + 127) / 128, 4), 256, 0, stream>>>(x, projW1T, hbf);
  conv_ln_kernel<true, true><<<(NN + 3) / 4, 256, 0, stream>>>(
      hbf, esrc, eom, rowptr, gamma, beta, h1);

  // ---- layer 1: g2 = h1 @ W2  ->  out = LN(gather(g2)) ----
  bmm_g_kernel<<<dim3((NN + 127) / 128, CC), 256, 0, stream>>>(h1, W2T, hbf);
  conv_ln_kernel<false, false><<<(NN + 3) / 4, 256, 0, stream>>>(
      hbf, esrc, eom, rowptr, gamma, beta, d_out);
}

// Round 7
// 411.751 us; speedup vs baseline: 3.8827x; 1.2218x over previous
//
#include <hip/hip_runtime.h>

#define NN 50000
#define NE 800000
#define DD 256
#define CC 8
#define HH 64
#define CHW 512   // C*H
#define LN_EPS 1e-5f
#define SCAN_BLOCKS ((NN + 1023) / 1024)  // 49

typedef __attribute__((ext_vector_type(8))) __bf16 bf16x8;
typedef __attribute__((ext_vector_type(4))) float f32x4;

// round-to-nearest-even f32 -> bf16 (values are finite here)
__device__ inline ushort f2bf(float f) {
  uint u = __float_as_uint(f);
  return (ushort)((u + 0x7fffu + ((u >> 16) & 1u)) >> 16);
}

__device__ inline float om_decode(uint4 om, int c) {
  uint wd = (c & 2) ? ((c & 4) ? om.w : om.y) : ((c & 4) ? om.z : om.x);
  ushort hu = (c & 1) ? (ushort)(wd >> 16) : (ushort)(wd & 0xffffu);
  union { ushort u; _Float16 f; } cv; cv.u = hu;
  return (float)cv.f;
}

// accumulate 8 bf16 lanes of hv (packed in uint4) scaled by wt into acc[8]
__device__ inline void acc8(float* acc, uint4 hv, float wt) {
  acc[0] += wt * __uint_as_float(hv.x << 16);
  acc[1] += wt * __uint_as_float(hv.x & 0xffff0000u);
  acc[2] += wt * __uint_as_float(hv.y << 16);
  acc[3] += wt * __uint_as_float(hv.y & 0xffff0000u);
  acc[4] += wt * __uint_as_float(hv.z << 16);
  acc[5] += wt * __uint_as_float(hv.z & 0xffff0000u);
  acc[6] += wt * __uint_as_float(hv.w << 16);
  acc[7] += wt * __uint_as_float(hv.w & 0xffff0000u);
}

// ---------------- fold: projW1T[n][d] = sum_k proj[d][c*64+k] * W1[c][k][i]
__global__ __launch_bounds__(256) void fold_w1_kernel(
    const float* __restrict__ proj, const float* __restrict__ W1,
    ushort* __restrict__ projW1T) {
  __shared__ float wl[64];
  const int n = blockIdx.x;           // 0..511
  const int c = n >> 6, i = n & 63;
  const int tid = threadIdx.x;
  if (tid < 64) wl[tid] = W1[c * 4096 + tid * 64 + i];
  __syncthreads();
  const float* pr = proj + (size_t)tid * 512 + c * 64;  // row d = tid
  float acc = 0.f;
#pragma unroll
  for (int k = 0; k < 64; ++k) acc += pr[k] * wl[k];
  projW1T[(size_t)n * 256 + tid] = f2bf(acc);
}

// ---------------- W2T[c][n][k] = W2[c][k][n], bf16 (B-operand layout) --------
__global__ __launch_bounds__(256) void w2t_kernel(const float* __restrict__ W2,
                                                  ushort* __restrict__ W2T) {
  int c = blockIdx.x;
  for (int idx = threadIdx.x; idx < 4096; idx += 256) {
    int nn = idx >> 6, k = idx & 63;
    W2T[(size_t)c * 4096 + idx] = f2bf(W2[(size_t)c * 4096 + k * 64 + nn]);
  }
}

// ---------------- MFMA GEMM: g1[N,512](bf16) = x[N,256] @ projW1 -------------
__global__ __launch_bounds__(256) void gemm_proj_kernel(
    const float* __restrict__ x, const ushort* __restrict__ BT,
    ushort* __restrict__ gout) {
  __shared__ ushort As[128 * 40];  // 10 KB
  __shared__ ushort Bs[128 * 40];  // 10 KB
  const int tid = threadIdx.x;
  const int lane = tid & 63, wv = tid >> 6;
  const int wm = wv >> 1, wn = wv & 1;
  const int lr = lane & 15, kg = lane >> 4;
  const int row0 = blockIdx.x * 128;
  const int col0 = blockIdx.y * 128;

  f32x4 acc[4][4];
#pragma unroll
  for (int i = 0; i < 4; ++i)
#pragma unroll
    for (int j = 0; j < 4; ++j) acc[i][j] = (f32x4){0.f, 0.f, 0.f, 0.f};

  for (int kk = 0; kk < 8; ++kk) {
    __syncthreads();
#pragma unroll
    for (int i = 0; i < 4; ++i) {
      int idx = tid + i * 256;
      int row = idx >> 3, quad = idx & 7;
      int rg = row0 + row;
      rg = rg < NN ? rg : NN - 1;
      float4 v = *(const float4*)(x + (size_t)rg * 256 + kk * 32 + quad * 4);
      ushort4 o = {f2bf(v.x), f2bf(v.y), f2bf(v.z), f2bf(v.w)};
      *(ushort4*)(As + row * 40 + quad * 4) = o;
    }
#pragma unroll
    for (int i = 0; i < 2; ++i) {
      int idx = tid + i * 256;
      int n = idx >> 2, quad = idx & 3;
      uint4 v = *(const uint4*)(BT + (size_t)(col0 + n) * 256 + kk * 32 + quad * 8);
      *(uint4*)(Bs + n * 40 + quad * 8) = v;
    }
    __syncthreads();
    bf16x8 a[4], b[4];
#pragma unroll
    for (int i = 0; i < 4; ++i)
      a[i] = *(const bf16x8*)(As + (wm * 64 + i * 16 + lr) * 40 + kg * 8);
#pragma unroll
    for (int j = 0; j < 4; ++j)
      b[j] = *(const bf16x8*)(Bs + (wn * 64 + j * 16 + lr) * 40 + kg * 8);
#pragma unroll
    for (int i = 0; i < 4; ++i)
#pragma unroll
      for (int j = 0; j < 4; ++j)
        acc[i][j] = __builtin_amdgcn_mfma_f32_16x16x32_bf16(a[i], b[j], acc[i][j], 0, 0, 0);
  }

  const int orow = kg * 4;
  const int ocol = lane & 15;
#pragma unroll
  for (int i = 0; i < 4; ++i) {
    int rg0 = row0 + wm * 64 + i * 16 + orow;
#pragma unroll
    for (int q = 0; q < 4; ++q) {
      int rg = rg0 + q;
      if (rg < NN) {
#pragma unroll
        for (int j = 0; j < 4; ++j) {
          gout[(size_t)rg * 512 + col0 + wn * 64 + j * 16 + ocol] = f2bf(acc[i][j][q]);
        }
      }
    }
  }
}

// ---------------- bmm: g2[n, c*64..] = h1[n, c*64..] @ W2[c]  (bf16 MFMA) ----
__global__ __launch_bounds__(256) void bmm_g_kernel(
    const ushort* __restrict__ h, const ushort* __restrict__ WT,
    ushort* __restrict__ g) {
  __shared__ ushort As[128 * 72];   // 18 KB
  __shared__ ushort Bs[64 * 72];    // 9 KB
  __shared__ float Cs[4][32 * 68];  // 34.8 KB
  const int tid = threadIdx.x, lane = tid & 63, wv = tid >> 6;
  const int lr = lane & 15, kg = lane >> 4;
  const int n0 = blockIdx.x * 128;
  const int c = blockIdx.y;

#pragma unroll
  for (int i = 0; i < 4; ++i) {
    int idx = tid + i * 256;
    int row = idx >> 3, q = idx & 7;
    int rg = n0 + row;
    rg = rg < NN ? rg : NN - 1;
    *(uint4*)(As + row * 72 + q * 8) =
        *(const uint4*)(h + (size_t)rg * 512 + c * 64 + q * 8);
  }
#pragma unroll
  for (int i = 0; i < 2; ++i) {
    int idx = tid + i * 256;
    int row = idx >> 3, q = idx & 7;
    *(uint4*)(Bs + row * 72 + q * 8) =
        *(const uint4*)(WT + (size_t)c * 4096 + row * 64 + q * 8);
  }
  __syncthreads();

  f32x4 acc[2][4];
#pragma unroll
  for (int m = 0; m < 2; ++m)
#pragma unroll
    for (int j = 0; j < 4; ++j) acc[m][j] = (f32x4){0.f, 0.f, 0.f, 0.f};

#pragma unroll
  for (int ks = 0; ks < 2; ++ks) {
    bf16x8 a[2], b[4];
#pragma unroll
    for (int m = 0; m < 2; ++m)
      a[m] = *(const bf16x8*)(As + (wv * 32 + m * 16 + lr) * 72 + ks * 32 + kg * 8);
#pragma unroll
    for (int j = 0; j < 4; ++j)
      b[j] = *(const bf16x8*)(Bs + (j * 16 + lr) * 72 + ks * 32 + kg * 8);
#pragma unroll
    for (int m = 0; m < 2; ++m)
#pragma unroll
      for (int j = 0; j < 4; ++j)
        acc[m][j] = __builtin_amdgcn_mfma_f32_16x16x32_bf16(a[m], b[j], acc[m][j], 0, 0, 0);
  }

  float* cs = &Cs[wv][0];
#pragma unroll
  for (int m = 0; m < 2; ++m)
#pragma unroll
    for (int j = 0; j < 4; ++j)
#pragma unroll
      for (int q = 0; q < 4; ++q)
        cs[(m * 16 + kg * 4 + q) * 68 + j * 16 + lr] = acc[m][j][q];
  __syncthreads();

  const int row = lane & 31, half = lane >> 5;
  const int rg = n0 + wv * 32 + row;
  if (rg < NN) {
    const float* rp = cs + row * 68 + half * 32;
    ushort ob[32];
#pragma unroll
    for (int t = 0; t < 32; ++t) ob[t] = f2bf(rp[t]);
    ushort* op = g + (size_t)rg * 512 + c * 64 + half * 32;
#pragma unroll
    for (int t = 0; t < 4; ++t)
      *(uint4*)(op + t * 8) = *(uint4*)(ob + t * 8);
  }
}

// ---------------- CSR build: histogram -> hierarchical scan -> fill ----------
__global__ void hist_kernel(const int* __restrict__ dst, int* __restrict__ cnt) {
  int e = blockIdx.x * 256 + threadIdx.x;
  if (e < NE) atomicAdd(&cnt[dst[e]], 1);
}

// per-1024-chunk totals
__global__ __launch_bounds__(1024) void scan1_kernel(const int* __restrict__ cnt,
                                                     int* __restrict__ blocksum) {
  __shared__ int ws[16];
  int tid = threadIdx.x, t = blockIdx.x * 1024 + tid;
  int v = (t < NN) ? cnt[t] : 0;
#pragma unroll
  for (int off = 32; off; off >>= 1) v += __shfl_xor(v, off);
  if ((tid & 63) == 0) ws[tid >> 6] = v;
  __syncthreads();
  if (tid < 16) {
    int s = ws[tid];
#pragma unroll
    for (int off = 8; off; off >>= 1) s += __shfl_xor(s, off, 16);
    if (tid == 0) blocksum[blockIdx.x] = s;
  }
}

// single wave scans the 49 block sums (exclusive); writes total to rowptr[NN]
__global__ __launch_bounds__(64) void scan2_kernel(int* __restrict__ blocksum,
                                                   int* __restrict__ rowptr) {
  int tid = threadIdx.x;
  int v = (tid < SCAN_BLOCKS) ? blocksum[tid] : 0;
  int orig = v;
#pragma unroll
  for (int off = 1; off < 64; off <<= 1) {
    int u = __shfl_up(v, off);
    if (tid >= off) v += u;
  }
  if (tid < SCAN_BLOCKS) blocksum[tid] = v - orig;  // exclusive
  if (tid == 63) rowptr[NN] = v;                    // total (=NE)
}

// full per-chunk exclusive scan + chunk offset -> rowptr & cursor
__global__ __launch_bounds__(1024) void scan3_kernel(const int* __restrict__ blocksum,
                                                     int* __restrict__ cntcur,
                                                     int* __restrict__ rowptr) {
  __shared__ int ws[16];
  int tid = threadIdx.x, lane = tid & 63, wv = tid >> 6;
  int t = blockIdx.x * 1024 + tid;
  int orig = (t < NN) ? cntcur[t] : 0;
  int v = orig;
#pragma unroll
  for (int off = 1; off < 64; off <<= 1) {
    int u = __shfl_up(v, off);
    if (lane >= off) v += u;
  }
  if (lane == 63) ws[wv] = v;
  __syncthreads();
  if (tid < 16) {
    int s = ws[tid];
#pragma unroll
    for (int off = 1; off < 16; off <<= 1) {
      int u = __shfl_up(s, off, 16);
      if (tid >= off) s += u;
    }
    ws[tid] = s;
  }
  __syncthreads();
  if (t < NN) {
    int excl = blocksum[blockIdx.x] + (wv ? ws[wv - 1] : 0) + (v - orig);
    rowptr[t] = excl;
    cntcur[t] = excl;
  }
}

// fill: CSR payload = src node + omega row packed f16x8
__global__ void fill_kernel(const int* __restrict__ dst, const int* __restrict__ src,
                            const float* __restrict__ omega, int* __restrict__ cursor,
                            int* __restrict__ esrc, uint4* __restrict__ eom) {
  int e = blockIdx.x * 256 + threadIdx.x;
  if (e < NE) {
    int d = dst[e];
    int pos = atomicAdd(&cursor[d], 1);
    esrc[pos] = src[e];
    const float4* om4 = (const float4*)(omega + (size_t)e * 8);
    float4 o0 = om4[0], o1 = om4[1];
    union { _Float16 f[8]; uint4 v; } pk;
    pk.f[0] = (_Float16)o0.x; pk.f[1] = (_Float16)o0.y;
    pk.f[2] = (_Float16)o0.z; pk.f[3] = (_Float16)o0.w;
    pk.f[4] = (_Float16)o1.x; pk.f[5] = (_Float16)o1.y;
    pk.f[6] = (_Float16)o1.z; pk.f[7] = (_Float16)o1.w;
    eom[pos] = pk.v;
  }
}

// ---------------- conv + LayerNorm (+ReLU) fused, 4x-unrolled gather ---------
// out[n,c,:] = LN( sum_{e in in(n)} omega[e,c] * g[src_e, c, :] )
template <bool RELU, bool BF16OUT>
__global__ __launch_bounds__(256) void conv_ln_kernel(
    const ushort* __restrict__ g, const int* __restrict__ esrc,
    const uint4* __restrict__ eom, const int* __restrict__ rowptr,
    const float* __restrict__ gamma, const float* __restrict__ beta,
    void* __restrict__ outv) {
  int n = blockIdx.x * 4 + (threadIdx.x >> 6);
  if (n >= NN) return;
  const int lane = threadIdx.x & 63;
  const int c = lane >> 3;          // channel of this lane
  const int i0 = (lane & 7) * 8;    // H-offset of this lane's 8 elements
  int start = rowptr[n], end = rowptr[n + 1];
  const uint4* g4 = (const uint4*)g;
  float acc[8] = {0.f, 0.f, 0.f, 0.f, 0.f, 0.f, 0.f, 0.f};

  int idx = start;
  // 4x unroll: 4 independent 1KB gathers in flight per wave
  for (; idx + 3 < end; idx += 4) {
    int s0 = esrc[idx], s1 = esrc[idx + 1], s2 = esrc[idx + 2], s3 = esrc[idx + 3];
    uint4 om0 = eom[idx], om1 = eom[idx + 1], om2 = eom[idx + 2], om3 = eom[idx + 3];
    uint4 h0 = g4[(size_t)s0 * 64 + lane];
    uint4 h1 = g4[(size_t)s1 * 64 + lane];
    uint4 h2 = g4[(size_t)s2 * 64 + lane];
    uint4 h3 = g4[(size_t)s3 * 64 + lane];
    float w0 = om_decode(om0, c), w1 = om_decode(om1, c);
    float w2 = om_decode(om2, c), w3 = om_decode(om3, c);
    acc8(acc, h0, w0);
    acc8(acc, h1, w1);
    acc8(acc, h2, w2);
    acc8(acc, h3, w3);
  }
  for (; idx < end; ++idx) {
    int s = esrc[idx];
    uint4 om = eom[idx];
    uint4 hv = g4[(size_t)s * 64 + lane];
    acc8(acc, hv, om_decode(om, c));
  }

  // LayerNorm over the 64 H-values of channel c (8 lanes x 8 each)
  float s8 = ((acc[0] + acc[1]) + (acc[2] + acc[3])) +
             ((acc[4] + acc[5]) + (acc[6] + acc[7]));
  s8 += __shfl_xor(s8, 1);
  s8 += __shfl_xor(s8, 2);
  s8 += __shfl_xor(s8, 4);
  float mu = s8 * (1.f / 64.f);
  float d[8];
  float v = 0.f;
#pragma unroll
  for (int j = 0; j < 8; ++j) {
    d[j] = acc[j] - mu;
    v += d[j] * d[j];
  }
  v += __shfl_xor(v, 1);
  v += __shfl_xor(v, 2);
  v += __shfl_xor(v, 4);
  float inv = rsqrtf(v * (1.f / 64.f) + LN_EPS);
  float4 g0 = *(const float4*)(gamma + i0);
  float4 g1 = *(const float4*)(gamma + i0 + 4);
  float4 b0 = *(const float4*)(beta + i0);
  float4 b1 = *(const float4*)(beta + i0 + 4);
  float gg[8] = {g0.x, g0.y, g0.z, g0.w, g1.x, g1.y, g1.z, g1.w};
  float bb[8] = {b0.x, b0.y, b0.z, b0.w, b1.x, b1.y, b1.z, b1.w};
  float y[8];
#pragma unroll
  for (int j = 0; j < 8; ++j) {
    float t = d[j] * inv * gg[j] + bb[j];
    y[j] = RELU ? fmaxf(t, 0.f) : t;
  }
  if (BF16OUT) {
    ushort o[8];
#pragma unroll
    for (int j = 0; j < 8; ++j) o[j] = f2bf(y[j]);
    *(uint4*)((ushort*)outv + (size_t)n * 512 + c * 64 + i0) = *(uint4*)o;
  } else {
    float* op = (float*)outv + (size_t)n * 512 + c * 64 + i0;
    *(float4*)op = make_float4(y[0], y[1], y[2], y[3]);
    *(float4*)(op + 4) = make_float4(y[4], y[5], y[6], y[7]);
  }
}

extern "C" void kernel_launch(void* const* d_in, const int* in_sizes, int n_in,
                              void* d_out, int out_size, void* d_ws, size_t ws_size,
                              hipStream_t stream) {
  const float* x     = (const float*)d_in[0];
  const int*   edge  = (const int*)d_in[1];   // [2,E]: src then dst
  const float* omega = (const float*)d_in[2]; // [E,8]
  const float* proj  = (const float*)d_in[3]; // [256,512]
  const float* W1    = (const float*)d_in[4]; // [8,64,64]
  const float* W2    = (const float*)d_in[5];
  const float* gamma = (const float*)d_in[6];
  const float* beta  = (const float*)d_in[7];
  const int* src = edge;
  const int* dst = edge + NE;

  // ws layout (16B-aligned): hbf | eom | esrc | rowptr | cntcur | blocksum | projW1T | W2T
  char* p = (char*)d_ws;
  ushort* hbf    = (ushort*)p;              p += (size_t)NN * CHW * 2;   // 51.2 MB
  uint4*  eom    = (uint4*)p;               p += (size_t)NE * 16;        // 12.8 MB
  int*    esrc   = (int*)p;                 p += (size_t)NE * 4;         // 3.2 MB
  int*    rowptr = (int*)p;                 p += (size_t)(NN + 16) * 4;
  int*    cntcur = (int*)p;                 p += (size_t)(NN + 16) * 4;
  int*    blocksum=(int*)p;                 p += (size_t)64 * 4;
  ushort* projW1T= (ushort*)p;              p += (size_t)512 * 256 * 2;
  ushort* W2T    = (ushort*)p;

  ushort* h1 = (ushort*)d_out;  // h1 bf16 in d_out's first half (dead before
                                // the final f32 write overwrites it)

  // ---- CSR build ----
  hipMemsetAsync(cntcur, 0, NN * sizeof(int), stream);
  hist_kernel<<<(NE + 255) / 256, 256, 0, stream>>>(dst, cntcur);
  scan1_kernel<<<SCAN_BLOCKS, 1024, 0, stream>>>(cntcur, blocksum);
  scan2_kernel<<<1, 64, 0, stream>>>(blocksum, rowptr);
  scan3_kernel<<<SCAN_BLOCKS, 1024, 0, stream>>>(blocksum, cntcur, rowptr);
  fill_kernel<<<(NE + 255) / 256, 256, 0, stream>>>(dst, src, omega, cntcur, esrc, eom);

  // ---- parameter prep ----
  fold_w1_kernel<<<512, 256, 0, stream>>>(proj, W1, projW1T);
  w2t_kernel<<<8, 256, 0, stream>>>(W2, W2T);

  // ---- layer 0: g1 = x @ projW1  ->  h1 = ReLU(LN(gather(g1))) ----
  gemm_proj_kernel<<<dim3((NN + 127) / 128, 4), 256, 0, stream>>>(x, projW1T, hbf);
  conv_ln_kernel<true, true><<<(NN + 3) / 4, 256, 0, stream>>>(
      hbf, esrc, eom, rowptr, gamma, beta, h1);

  // ---- layer 1: g2 = h1 @ W2  ->  out = LN(gather(g2)) ----
  bmm_g_kernel<<<dim3((NN + 127) / 128, CC), 256, 0, stream>>>(h1, W2T, hbf);
  conv_ln_kernel<false, false><<<(NN + 3) / 4, 256, 0, stream>>>(
      hbf, esrc, eom, rowptr, gamma, beta, d_out);
}